// Round 3
// baseline (181.812 us; speedup 1.0000x reference)
//
#include <hip/hip_runtime.h>

// ---------- types ----------
typedef __bf16 bf16x8 __attribute__((ext_vector_type(8)));
typedef float f32x4 __attribute__((ext_vector_type(4)));
typedef float f32x16 __attribute__((ext_vector_type(16)));

__device__ __forceinline__ unsigned short f2bf(float f) {
    return __builtin_bit_cast(unsigned short, (__bf16)f);
}

__device__ __forceinline__ float bf2f(unsigned short u) {
    unsigned int x = ((unsigned int)u) << 16;
    return __builtin_bit_cast(float, x);
}

__device__ __forceinline__ unsigned int packbf2(float a, float b) {
    unsigned short lo = f2bf(a), hi = f2bf(b);
    return (unsigned int)lo | ((unsigned int)hi << 16);
}

__device__ __forceinline__ bf16x8 load_frag(const unsigned short* p) {
    int4 v = *reinterpret_cast<const int4*>(p);
    return __builtin_bit_cast(bf16x8, v);
}

__device__ __forceinline__ void gload_lds16(const unsigned short* g, unsigned short* l) {
    __builtin_amdgcn_global_load_lds((const __attribute__((address_space(1))) void*)g,
                                     (__attribute__((address_space(3))) void*)l, 16, 0, 0);
}

// ---------- small converters ----------
__global__ __launch_bounds__(256) void f32_to_bf16(const float* __restrict__ in,
                                                   unsigned short* __restrict__ out, int n) {
    int i = blockIdx.x * 256 + threadIdx.x;
    if (i < n) out[i] = f2bf(in[i]);
}

__global__ __launch_bounds__(256) void concat_w(const float* __restrict__ wq,
                                                const float* __restrict__ wk,
                                                const float* __restrict__ wv,
                                                unsigned short* __restrict__ out) {
    int i = blockIdx.x * 256 + threadIdx.x;      // 0 .. 3*1024*1024-1
    int r = i >> 20;
    const float* src = (r == 0) ? wq : ((r == 1) ? wk : wv);
    out[i] = f2bf(src[i & 1048575]);
}

__global__ __launch_bounds__(256) void rope_table(float* __restrict__ cost,
                                                  float* __restrict__ sint) {
    int i = blockIdx.x * 256 + threadIdx.x;      // 2048*32
    int t = i >> 5, d = i & 31;
    float inv = powf(10000.0f, -(float)d / 32.0f);
    float f = (float)t * inv;
    cost[i] = cosf(f);
    sint[i] = sinf(f);
}

// ---------- GEMM (m97 structure): C[M,N] = A[M,K] @ B[N,K]^T ----------
// 128x128 tile, BK=64, 4 waves, global_load_lds width-16, linear LDS.
template <bool BF16OUT>
__global__ __launch_bounds__(256) void gemm_m97(const unsigned short* __restrict__ A,
                                                const unsigned short* __restrict__ B,
                                                void* __restrict__ Cv,
                                                int N, int K) {
    __shared__ __align__(16) unsigned short As[128 * 64];
    __shared__ __align__(16) unsigned short Bs[128 * 64];
    int tid = threadIdx.x;
    int lane = tid & 63;
    int w = tid >> 6;
    int wm = w >> 1, wn = w & 1;
    int m0 = blockIdx.x * 128;
    int n0 = blockIdx.y * 128;
    int r8 = lane >> 3;        // 0..7
    int c8 = lane & 7;         // 0..7, x8 elems

    f32x4 acc[4][4] = {};

    for (int k0 = 0; k0 < K; k0 += 64) {
        __syncthreads();
#pragma unroll
        for (int c = 0; c < 4; ++c) {
            int row = 32 * w + 8 * c + r8;
            gload_lds16(&A[(size_t)(m0 + row) * K + k0 + c8 * 8], &As[(32 * w + 8 * c) * 64]);
            gload_lds16(&B[(size_t)(n0 + row) * K + k0 + c8 * 8], &Bs[(32 * w + 8 * c) * 64]);
        }
        __syncthreads();
#pragma unroll
        for (int kk = 0; kk < 2; ++kk) {
            int krd = kk * 32 + (lane >> 4) * 8;
            bf16x8 af[4], bfr[4];
#pragma unroll
            for (int i = 0; i < 4; ++i) af[i]  = load_frag(&As[(wm * 64 + i * 16 + (lane & 15)) * 64 + krd]);
#pragma unroll
            for (int j = 0; j < 4; ++j) bfr[j] = load_frag(&Bs[(wn * 64 + j * 16 + (lane & 15)) * 64 + krd]);
#pragma unroll
            for (int i = 0; i < 4; ++i)
#pragma unroll
                for (int j = 0; j < 4; ++j)
                    acc[i][j] = __builtin_amdgcn_mfma_f32_16x16x32_bf16(af[i], bfr[j], acc[i][j], 0, 0, 0);
        }
    }
    int r0 = (lane >> 4) * 4;
    int cc = lane & 15;
#pragma unroll
    for (int i = 0; i < 4; ++i)
#pragma unroll
        for (int j = 0; j < 4; ++j)
#pragma unroll
            for (int r = 0; r < 4; ++r) {
                size_t m = m0 + wm * 64 + i * 16 + r0 + r;
                size_t n = n0 + wn * 64 + j * 16 + cc;
                if constexpr (BF16OUT) {
                    ((unsigned short*)Cv)[m * N + n] = f2bf(acc[i][j][r]);
                } else {
                    ((float*)Cv)[m * N + n] = acc[i][j][r];
                }
            }
}

// ---------- post: rmsnorm + rope + scale for q,k; layout [B,H,T,64] bf16 ----------
__global__ __launch_bounds__(256) void postprocess_qk(const unsigned short* __restrict__ qkv, // bf16 [4096][3072]
                                                      const float* __restrict__ cost,
                                                      const float* __restrict__ sint,
                                                      unsigned short* __restrict__ qb,
                                                      unsigned short* __restrict__ kb) {
    int gid = blockIdx.x * 4 + (threadIdx.x >> 6);   // (b,t,h) row id, 0..65535
    int lane = threadIdx.x & 63;
    int h = gid & 15;
    int t = (gid >> 4) & 2047;
    int b = gid >> 15;
    int m = b * 2048 + t;

    float q = bf2f(qkv[(size_t)m * 3072 + h * 64 + lane]);
    float k = bf2f(qkv[(size_t)m * 3072 + 1024 + h * 64 + lane]);

    float sq = q * q, sk = k * k;
    for (int msk = 1; msk < 64; msk <<= 1) {
        sq += __shfl_xor(sq, msk, 64);
        sk += __shfl_xor(sk, msk, 64);
    }
    q *= rsqrtf(sq * (1.0f / 64.0f) + 1e-6f);
    k *= rsqrtf(sk * (1.0f / 64.0f) + 1e-6f);

    int d = lane & 31;
    float c = cost[t * 32 + d], s = sint[t * 32 + d];
    float qp = __shfl_xor(q, 32, 64);
    float kp = __shfl_xor(k, 32, 64);
    float qo = (lane < 32) ? (q * c + qp * s) : (q * c - qp * s);
    float ko = (lane < 32) ? (k * c + kp * s) : (k * c - kp * s);
    qo *= 0.125f * 1.44269504088896f;   // fold softmax scale AND log2(e): attn uses exp2

    size_t oidx = ((size_t)((b * 16 + h) * 2048 + t)) * 64 + lane;
    qb[oidx] = f2bf(qo);
    kb[oidx] = f2bf(ko);
}

// ---------- v-lerp + transpose: qkv v-section + v1 -> vt [bh][64][2048] ----------
__global__ __launch_bounds__(256) void lerp_transpose_v(const unsigned short* __restrict__ qkvb,
                                                        const float* __restrict__ v1,
                                                        const float* __restrict__ lamb_p,
                                                        unsigned short* __restrict__ vt) {
    __shared__ __align__(16) unsigned short tile[64][72];
    int bh = blockIdx.y;
    int b = bh >> 4, h = bh & 15;
    int t0 = blockIdx.x * 64;
    int tid = threadIdx.x;
    int r = tid >> 3;            // 0..31
    int c = (tid & 7) * 8;       // 0..56
    float lamb = lamb_p[0];
    float oml = 1.0f - lamb;

#pragma unroll
    for (int half = 0; half < 2; ++half) {
        int row = r + half * 32;
        int m = b * 2048 + t0 + row;
        int4 vv = *reinterpret_cast<const int4*>(&qkvb[(size_t)m * 3072 + 2048 + h * 64 + c]);
        const unsigned short* vs = reinterpret_cast<const unsigned short*>(&vv);
        const float* v1p = &v1[((size_t)m * 16 + h) * 64 + c];
        float4 va = *reinterpret_cast<const float4*>(v1p);
        float4 vb4 = *reinterpret_cast<const float4*>(v1p + 4);
        float v1a[8] = {va.x, va.y, va.z, va.w, vb4.x, vb4.y, vb4.z, vb4.w};
        unsigned short tmp[8];
#pragma unroll
        for (int j = 0; j < 8; ++j) tmp[j] = f2bf(oml * bf2f(vs[j]) + lamb * v1a[j]);
        *reinterpret_cast<int4*>(&tile[row][c]) = *reinterpret_cast<int4*>(tmp);
    }
    __syncthreads();
    unsigned short* dst = vt + (size_t)bh * 64 * 2048 + t0;
    unsigned short tmp[8];
#pragma unroll
    for (int j = 0; j < 8; ++j) tmp[j] = tile[c + j][r];
    *reinterpret_cast<int4*>(&dst[(size_t)r * 2048 + c]) = *reinterpret_cast<int4*>(tmp);
#pragma unroll
    for (int j = 0; j < 8; ++j) tmp[j] = tile[c + j][r + 32];
    *reinterpret_cast<int4*>(&dst[(size_t)(r + 32) * 2048 + c]) = *reinterpret_cast<int4*>(tmp);
}

// ---------- flash attention, causal, swapped-QK^T 32x32 MFMA ----------
// 4 waves x 32 q rows = 128 q/block; double-buffered K/V LDS, 1 barrier/tile;
// fixed softmax max (|s| <= 8*log2e by unit-RMS rows); exp2; permlane32_swap P-assembly.
__global__ __launch_bounds__(256) void attn(const unsigned short* __restrict__ qb,
                                            const unsigned short* __restrict__ kb,
                                            const unsigned short* __restrict__ vt,  // [bh][64][2048]
                                            unsigned short* __restrict__ yb) {      // [B,T,1024]
    __shared__ __align__(16) unsigned short Ks[2][64][72];   // [buf][kv][d]
    __shared__ __align__(16) unsigned short Vt[2][64][72];   // [buf][d][kv]
    int tid = threadIdx.x;
    int lane = tid & 63;
    int w = tid >> 6;
    int hi = lane >> 5;
    int l31 = lane & 31;

    int bid = blockIdx.x;
    int i = bid >> 5;
    int bh = bid & 31;
    int qt = (i < 8) ? (15 - i) : (i - 8);   // heavy blocks first
    int q0 = qt * 128;
    int b = bh >> 4, h = bh & 15;
    const size_t base = (size_t)bh * 2048 * 64;
    const unsigned short* vtb = vt + (size_t)bh * 64 * 2048;
    int ktmax = 2 * qt + 1;

    bf16x8 qf[4];
    int qrow = q0 + w * 32 + l31;
#pragma unroll
    for (int kd = 0; kd < 4; ++kd)
        qf[kd] = load_frag(&qb[base + (size_t)qrow * 64 + kd * 16 + hi * 8]);

    f32x16 oacc[2] = {};
    float lrun = 0.0f;

    int srow = tid >> 3;            // 0..31
    int scol = (tid & 7) * 8;       // 0..56
    int4 kr0, kr1, vr0, vr1;
#define LOADT(kt_)                                                                                    \
    do {                                                                                              \
        kr0 = *reinterpret_cast<const int4*>(&kb[base + (size_t)((kt_)*64 + srow) * 64 + scol]);      \
        kr1 = *reinterpret_cast<const int4*>(&kb[base + (size_t)((kt_)*64 + srow + 32) * 64 + scol]); \
        vr0 = *reinterpret_cast<const int4*>(&vtb[(size_t)srow * 2048 + (kt_)*64 + scol]);            \
        vr1 = *reinterpret_cast<const int4*>(&vtb[(size_t)(srow + 32) * 2048 + (kt_)*64 + scol]);     \
    } while (0)
#define WRITET(p_)                                                          \
    do {                                                                    \
        *reinterpret_cast<int4*>(&Ks[p_][srow][scol]) = kr0;                \
        *reinterpret_cast<int4*>(&Ks[p_][srow + 32][scol]) = kr1;           \
        *reinterpret_cast<int4*>(&Vt[p_][srow][scol]) = vr0;                \
        *reinterpret_cast<int4*>(&Vt[p_][srow + 32][scol]) = vr1;           \
    } while (0)

    LOADT(0);
    WRITET(0);
    __syncthreads();

    int qwlo = q0 + w * 32;
    int p = 0;
    for (int kt = 0; kt <= ktmax; ++kt) {
        if (kt < ktmax) LOADT(kt + 1);

        bool compute = (kt * 64 <= qwlo + 31);
        unsigned int wA[2][4], wB[2][4];
        float rs0 = 0.0f, rs1 = 0.0f, rs2 = 0.0f, rs3 = 0.0f;
        if (compute) {
            f32x16 sacc[2] = {};
#pragma unroll
            for (int nt = 0; nt < 2; ++nt)
#pragma unroll
                for (int kd = 0; kd < 4; ++kd) {
                    bf16x8 kf = load_frag(&Ks[p][nt * 32 + l31][kd * 16 + hi * 8]);
                    sacc[nt] = __builtin_amdgcn_mfma_f32_32x32x16_bf16(kf, qf[kd], sacc[nt], 0, 0, 0);
                }

            bool diag = (kt * 64 + 63 > qwlo);
#pragma unroll
            for (int nt = 0; nt < 2; ++nt)
#pragma unroll
                for (int r = 0; r < 16; ++r) {
                    float s = sacc[nt][r];
                    if (diag) {
                        int kvg = kt * 64 + nt * 32 + (r & 3) + 8 * (r >> 2) + 4 * hi;
                        if (kvg > qrow) s = -3.0e38f;
                    }
                    float e = __builtin_amdgcn_exp2f(s);
                    sacc[nt][r] = e;
                    if ((r & 3) == 0) rs0 += e;
                    else if ((r & 3) == 1) rs1 += e;
                    else if ((r & 3) == 2) rs2 += e;
                    else rs3 += e;
                }
            float rs = (rs0 + rs1) + (rs2 + rs3);
            rs += __shfl_xor(rs, 32, 64);
            lrun += rs;

#pragma unroll
            for (int nt = 0; nt < 2; ++nt)
#pragma unroll
                for (int rr = 0; rr < 4; ++rr) {
                    wA[nt][rr] = packbf2(sacc[nt][4 * rr + 0], sacc[nt][4 * rr + 1]);
                    wB[nt][rr] = packbf2(sacc[nt][4 * rr + 2], sacc[nt][4 * rr + 3]);
                }
        }

        if (kt < ktmax) WRITET(p ^ 1);

        if (compute) {
#pragma unroll
            for (int ks = 0; ks < 4; ++ks) {
                int nt = ks >> 1;
                int b2 = (ks & 1) * 2;
                // permlane32_swap(a,b): new_a = {a_lo, b_lo}, new_b = {a_hi, b_hi}
                auto rA = __builtin_amdgcn_permlane32_swap(wA[nt][b2], wA[nt][b2 + 1], false, false);
                auto rB = __builtin_amdgcn_permlane32_swap(wB[nt][b2], wB[nt][b2 + 1], false, false);
                uint4 pa;
                pa.x = rA[0];   // kv 16ks+8hi+{0,1}
                pa.y = rB[0];   // +{2,3}
                pa.z = rA[1];   // +{4,5}
                pa.w = rB[1];   // +{6,7}
                bf16x8 paf = __builtin_bit_cast(bf16x8, pa);
#pragma unroll
                for (int dt = 0; dt < 2; ++dt) {
                    bf16x8 vtf = load_frag(&Vt[p][dt * 32 + l31][ks * 16 + hi * 8]);
                    oacc[dt] = __builtin_amdgcn_mfma_f32_32x32x16_bf16(paf, vtf, oacc[dt], 0, 0, 0);
                }
            }
        }
        __syncthreads();
        p ^= 1;
    }

    float linv = 1.0f / lrun;
#pragma unroll
    for (int r = 0; r < 16; ++r) {
        int ql = (r & 3) + 8 * (r >> 2) + 4 * hi;
        float rv = __shfl(linv, ql, 64);
        int q = q0 + w * 32 + ql;
        size_t ro = ((size_t)(b * 2048 + q) * 16 + h) * 64;
        yb[ro + l31]      = f2bf(oacc[0][r] * rv);
        yb[ro + 32 + l31] = f2bf(oacc[1][r] * rv);
    }
#undef LOADT
#undef WRITET
}

// ---------- launch ----------
extern "C" void kernel_launch(void* const* d_in, const int* in_sizes, int n_in,
                              void* d_out, int out_size, void* d_ws, size_t ws_size,
                              hipStream_t stream) {
    const float* x      = (const float*)d_in[0];   // [2,2048,1024]
    const float* v1     = (const float*)d_in[1];   // [2,2048,16,64]
    const float* w_q    = (const float*)d_in[2];
    const float* w_k    = (const float*)d_in[3];
    const float* w_v    = (const float*)d_in[4];
    const float* w_proj = (const float*)d_in[5];
    const float* lamb   = (const float*)d_in[6];
    float* out = (float*)d_out;

    char* ws = (char*)d_ws;
    unsigned short* xb      = (unsigned short*)(ws + 0);           // 8MB
    unsigned short* wqkv_b  = (unsigned short*)(ws + (8u  << 20)); // 6MB
    unsigned short* wproj_b = (unsigned short*)(ws + (14u << 20)); // 2MB
    unsigned short* qkvb    = (unsigned short*)(ws + (16u << 20)); // bf16 [4096][3072] = 24MB
    unsigned short* vtp     = (unsigned short*)(ws + (40u << 20)); // [32][64][2048] = 8MB
    unsigned short* qbuf    = (unsigned short*)(ws + (48u << 20)); // 8MB
    unsigned short* kbuf    = (unsigned short*)(ws + (56u << 20)); // 8MB
    unsigned short* ybuf    = (unsigned short*)(ws + (64u << 20)); // 8MB
    float*          cost    = (float*)        (ws + (72u << 20));
    float*          sint    = (float*)        (ws + (72u << 20) + 262144);

    f32_to_bf16<<<16384, 256, 0, stream>>>(x, xb, 4096 * 1024);
    concat_w<<<12288, 256, 0, stream>>>(w_q, w_k, w_v, wqkv_b);
    f32_to_bf16<<<4096, 256, 0, stream>>>(w_proj, wproj_b, 1024 * 1024);
    rope_table<<<256, 256, 0, stream>>>(cost, sint);

    gemm_m97<true><<<dim3(32, 24), 256, 0, stream>>>(xb, wqkv_b, (void*)qkvb, 3072, 1024);

    postprocess_qk<<<16384, 256, 0, stream>>>(qkvb, cost, sint, qbuf, kbuf);
    lerp_transpose_v<<<dim3(32, 32), 256, 0, stream>>>(qkvb, v1, lamb, vtp);

    attn<<<512, 256, 0, stream>>>(qbuf, kbuf, vtp, ybuf);

    gemm_m97<false><<<dim3(32, 8), 256, 0, stream>>>(ybuf, wproj_b, (void*)out, 1024, 1024);

    hipMemcpyAsync(out + 4194304, v1, 4194304 * sizeof(float),
                   hipMemcpyDeviceToDevice, stream);
}

// Round 4
// 158.851 us; speedup vs baseline: 1.1445x; 1.1445x over previous
//
#include <hip/hip_runtime.h>

// ---------- types ----------
typedef __bf16 bf16x8 __attribute__((ext_vector_type(8)));
typedef float f32x4 __attribute__((ext_vector_type(4)));
typedef float f32x16 __attribute__((ext_vector_type(16)));

__device__ __forceinline__ unsigned short f2bf(float f) {
    return __builtin_bit_cast(unsigned short, (__bf16)f);
}

__device__ __forceinline__ float bf2f(unsigned short u) {
    unsigned int x = ((unsigned int)u) << 16;
    return __builtin_bit_cast(float, x);
}

__device__ __forceinline__ unsigned int packbf2(float a, float b) {
    unsigned short lo = f2bf(a), hi = f2bf(b);
    return (unsigned int)lo | ((unsigned int)hi << 16);
}

__device__ __forceinline__ bf16x8 load_frag(const unsigned short* p) {
    int4 v = *reinterpret_cast<const int4*>(p);
    return __builtin_bit_cast(bf16x8, v);
}

// ---------- small converters ----------
__global__ __launch_bounds__(256) void f32_to_bf16(const float* __restrict__ in,
                                                   unsigned short* __restrict__ out, int n) {
    int i = blockIdx.x * 256 + threadIdx.x;
    if (i < n) out[i] = f2bf(in[i]);
}

__global__ __launch_bounds__(256) void concat_w(const float* __restrict__ wq,
                                                const float* __restrict__ wk,
                                                const float* __restrict__ wv,
                                                unsigned short* __restrict__ out) {
    int i = blockIdx.x * 256 + threadIdx.x;      // 0 .. 3*1024*1024-1
    int r = i >> 20;
    const float* src = (r == 0) ? wq : ((r == 1) ? wk : wv);
    out[i] = f2bf(src[i & 1048575]);
}

__global__ __launch_bounds__(256) void rope_table(float* __restrict__ cost,
                                                  float* __restrict__ sint) {
    int i = blockIdx.x * 256 + threadIdx.x;      // 2048*32
    int t = i >> 5, d = i & 31;
    float inv = powf(10000.0f, -(float)d / 32.0f);
    float f = (float)t * inv;
    cost[i] = cosf(f);
    sint[i] = sinf(f);
}

// ---------- GEMM: C[M,N] = A[M,K] @ B[N,K]^T  (bf16 in; fp32 or bf16 out) ----------
#define GBM 128
#define GBN 128
#define GBK 64
#define GPAD 8

template <bool BF16OUT>
__global__ __launch_bounds__(256) void gemm_bf16(const unsigned short* __restrict__ A,
                                                 const unsigned short* __restrict__ B,
                                                 void* __restrict__ Cv,
                                                 int N, int K) {
    __shared__ __align__(16) unsigned short As[GBM][GBK + GPAD];
    __shared__ __align__(16) unsigned short Bs[GBN][GBK + GPAD];
    int tid = threadIdx.x;
    int lane = tid & 63;
    int wid = tid >> 6;
    int wm = wid >> 1, wn = wid & 1;
    int m0 = blockIdx.x * GBM;
    int n0 = blockIdx.y * GBN;

    f32x4 acc[4][4] = {};

    int lrow = tid >> 3;         // 0..31
    int lcol = (tid & 7) * 8;    // 0..56

    for (int k0 = 0; k0 < K; k0 += GBK) {
        __syncthreads();
        for (int rr = 0; rr < 4; ++rr) {
            int row = rr * 32 + lrow;
            *reinterpret_cast<int4*>(&As[row][lcol]) =
                *reinterpret_cast<const int4*>(&A[(size_t)(m0 + row) * K + k0 + lcol]);
            *reinterpret_cast<int4*>(&Bs[row][lcol]) =
                *reinterpret_cast<const int4*>(&B[(size_t)(n0 + row) * K + k0 + lcol]);
        }
        __syncthreads();
        for (int kk = 0; kk < 2; ++kk) {
            int krd = kk * 32 + (lane >> 4) * 8;
            bf16x8 af[4], bfr[4];
            for (int i = 0; i < 4; ++i) af[i]  = load_frag(&As[wm * 64 + i * 16 + (lane & 15)][krd]);
            for (int j = 0; j < 4; ++j) bfr[j] = load_frag(&Bs[wn * 64 + j * 16 + (lane & 15)][krd]);
            for (int i = 0; i < 4; ++i)
                for (int j = 0; j < 4; ++j)
                    acc[i][j] = __builtin_amdgcn_mfma_f32_16x16x32_bf16(af[i], bfr[j], acc[i][j], 0, 0, 0);
        }
    }
    int r0 = (lane >> 4) * 4;
    int cc = lane & 15;
    for (int i = 0; i < 4; ++i)
        for (int j = 0; j < 4; ++j)
            for (int r = 0; r < 4; ++r) {
                size_t m = m0 + wm * 64 + i * 16 + r0 + r;
                size_t n = n0 + wn * 64 + j * 16 + cc;
                if constexpr (BF16OUT) {
                    ((unsigned short*)Cv)[m * N + n] = f2bf(acc[i][j][r]);
                } else {
                    ((float*)Cv)[m * N + n] = acc[i][j][r];
                }
            }
}

// ---------- post: rmsnorm + rope + scale for q,k; layout [B,H,T,64] bf16 ----------
__global__ __launch_bounds__(256) void postprocess_qk(const unsigned short* __restrict__ qkv, // bf16 [4096][3072]
                                                      const float* __restrict__ cost,
                                                      const float* __restrict__ sint,
                                                      unsigned short* __restrict__ qb,
                                                      unsigned short* __restrict__ kb) {
    int gid = blockIdx.x * 4 + (threadIdx.x >> 6);   // (b,t,h) row id, 0..65535
    int lane = threadIdx.x & 63;
    int h = gid & 15;
    int t = (gid >> 4) & 2047;
    int b = gid >> 15;
    int m = b * 2048 + t;

    float q = bf2f(qkv[(size_t)m * 3072 + h * 64 + lane]);
    float k = bf2f(qkv[(size_t)m * 3072 + 1024 + h * 64 + lane]);

    float sq = q * q, sk = k * k;
    for (int msk = 1; msk < 64; msk <<= 1) {
        sq += __shfl_xor(sq, msk, 64);
        sk += __shfl_xor(sk, msk, 64);
    }
    q *= rsqrtf(sq * (1.0f / 64.0f) + 1e-6f);
    k *= rsqrtf(sk * (1.0f / 64.0f) + 1e-6f);

    int d = lane & 31;
    float c = cost[t * 32 + d], s = sint[t * 32 + d];
    float qp = __shfl_xor(q, 32, 64);
    float kp = __shfl_xor(k, 32, 64);
    float qo = (lane < 32) ? (q * c + qp * s) : (q * c - qp * s);
    float ko = (lane < 32) ? (k * c + kp * s) : (k * c - kp * s);
    qo *= 0.125f * 1.44269504088896f;   // fold softmax scale AND log2(e): attn uses exp2

    size_t oidx = ((size_t)((b * 16 + h) * 2048 + t)) * 64 + lane;
    qb[oidx] = f2bf(qo);
    kb[oidx] = f2bf(ko);
}

// ---------- v-lerp + transpose: qkv v-section + v1 -> vt [bh][64][2048] ----------
__global__ __launch_bounds__(256) void lerp_transpose_v(const unsigned short* __restrict__ qkvb,
                                                        const float* __restrict__ v1,
                                                        const float* __restrict__ lamb_p,
                                                        unsigned short* __restrict__ vt) {
    __shared__ __align__(16) unsigned short tile[64][72];
    int bh = blockIdx.y;
    int b = bh >> 4, h = bh & 15;
    int t0 = blockIdx.x * 64;
    int tid = threadIdx.x;
    int r = tid >> 3;            // 0..31
    int c = (tid & 7) * 8;       // 0..56
    float lamb = lamb_p[0];
    float oml = 1.0f - lamb;

#pragma unroll
    for (int half = 0; half < 2; ++half) {
        int row = r + half * 32;
        int m = b * 2048 + t0 + row;
        int4 vv = *reinterpret_cast<const int4*>(&qkvb[(size_t)m * 3072 + 2048 + h * 64 + c]);
        const unsigned short* vs = reinterpret_cast<const unsigned short*>(&vv);
        const float* v1p = &v1[((size_t)m * 16 + h) * 64 + c];
        float4 va = *reinterpret_cast<const float4*>(v1p);
        float4 vb4 = *reinterpret_cast<const float4*>(v1p + 4);
        float v1a[8] = {va.x, va.y, va.z, va.w, vb4.x, vb4.y, vb4.z, vb4.w};
        unsigned short tmp[8];
#pragma unroll
        for (int j = 0; j < 8; ++j) tmp[j] = f2bf(oml * bf2f(vs[j]) + lamb * v1a[j]);
        *reinterpret_cast<int4*>(&tile[row][c]) = *reinterpret_cast<int4*>(tmp);
    }
    __syncthreads();
    unsigned short* dst = vt + (size_t)bh * 64 * 2048 + t0;
    unsigned short tmp[8];
#pragma unroll
    for (int j = 0; j < 8; ++j) tmp[j] = tile[c + j][r];
    *reinterpret_cast<int4*>(&dst[(size_t)r * 2048 + c]) = *reinterpret_cast<int4*>(tmp);
#pragma unroll
    for (int j = 0; j < 8; ++j) tmp[j] = tile[c + j][r + 32];
    *reinterpret_cast<int4*>(&dst[(size_t)(r + 32) * 2048 + c]) = *reinterpret_cast<int4*>(tmp);
}

// ---------- flash attention, causal, swapped-QK^T 32x32 MFMA ----------
// R2 schedule (proven): single-buffer LDS, stage->barrier->compute, next-tile
// loads issued before compute. VALU diet: exp2 (log2e prefolded), permlane32_swap
// P-assembly, cvt_pk-style bf16 packing. Fixed softmax max (|s|<=8*log2e).
__global__ __launch_bounds__(256) void attn(const unsigned short* __restrict__ qb,
                                            const unsigned short* __restrict__ kb,
                                            const unsigned short* __restrict__ vt,  // [bh][64][2048]
                                            unsigned short* __restrict__ yb) {      // [B,T,1024]
    __shared__ __align__(16) unsigned short Ks[64][72];   // [kv][d]
    __shared__ __align__(16) unsigned short Vt[64][72];   // [d][kv]
    int tid = threadIdx.x;
    int lane = tid & 63;
    int w = tid >> 6;
    int hi = lane >> 5;
    int l31 = lane & 31;

    int bid = blockIdx.x;
    int i = bid >> 5;
    int bh = bid & 31;
    int qt = (i < 8) ? (15 - i) : (i - 8);   // heavy blocks first; bid & bid+256 pair to const work
    int q0 = qt * 128;
    int b = bh >> 4, h = bh & 15;
    const size_t base = (size_t)bh * 2048 * 64;
    const unsigned short* vtb = vt + (size_t)bh * 64 * 2048;
    int ktmax = 2 * qt + 1;

    bf16x8 qf[4];
    int qrow = q0 + w * 32 + l31;
#pragma unroll
    for (int kd = 0; kd < 4; ++kd)
        qf[kd] = load_frag(&qb[base + (size_t)qrow * 64 + kd * 16 + hi * 8]);

    f32x16 oacc[2] = {};
    float lrun = 0.0f;

    int srow = tid >> 3;            // 0..31
    int scol = (tid & 7) * 8;       // 0..56
    int4 kr0, kr1, vr0, vr1;
#define LOADT(kt_)                                                                                    \
    do {                                                                                              \
        kr0 = *reinterpret_cast<const int4*>(&kb[base + (size_t)((kt_)*64 + srow) * 64 + scol]);      \
        kr1 = *reinterpret_cast<const int4*>(&kb[base + (size_t)((kt_)*64 + srow + 32) * 64 + scol]); \
        vr0 = *reinterpret_cast<const int4*>(&vtb[(size_t)srow * 2048 + (kt_)*64 + scol]);            \
        vr1 = *reinterpret_cast<const int4*>(&vtb[(size_t)(srow + 32) * 2048 + (kt_)*64 + scol]);     \
    } while (0)

    LOADT(0);
    int qwlo = q0 + w * 32;

    for (int kt = 0; kt <= ktmax; ++kt) {
        __syncthreads();
        *reinterpret_cast<int4*>(&Ks[srow][scol]) = kr0;
        *reinterpret_cast<int4*>(&Ks[srow + 32][scol]) = kr1;
        *reinterpret_cast<int4*>(&Vt[srow][scol]) = vr0;
        *reinterpret_cast<int4*>(&Vt[srow + 32][scol]) = vr1;
        __syncthreads();
        if (kt < ktmax) LOADT(kt + 1);

        if (kt * 64 <= qwlo + 31) {
            // S^T tiles: m = kv (32 per tile), n = q
            f32x16 sacc[2] = {};
#pragma unroll
            for (int nt = 0; nt < 2; ++nt)
#pragma unroll
                for (int kd = 0; kd < 4; ++kd) {
                    bf16x8 kf = load_frag(&Ks[nt * 32 + l31][kd * 16 + hi * 8]);
                    sacc[nt] = __builtin_amdgcn_mfma_f32_32x32x16_bf16(kf, qf[kd], sacc[nt], 0, 0, 0);
                }

            bool diag = (kt * 64 + 63 > qwlo);
            float rs0 = 0.0f, rs1 = 0.0f, rs2 = 0.0f, rs3 = 0.0f;
#pragma unroll
            for (int nt = 0; nt < 2; ++nt)
#pragma unroll
                for (int r = 0; r < 16; ++r) {
                    float s = sacc[nt][r];
                    if (diag) {
                        int kvg = kt * 64 + nt * 32 + (r & 3) + 8 * (r >> 2) + 4 * hi;
                        if (kvg > qrow) s = -3.0e38f;
                    }
                    float e = __builtin_amdgcn_exp2f(s);
                    sacc[nt][r] = e;
                    if ((r & 3) == 0) rs0 += e;
                    else if ((r & 3) == 1) rs1 += e;
                    else if ((r & 3) == 2) rs2 += e;
                    else rs3 += e;
                }
            float rs = (rs0 + rs1) + (rs2 + rs3);
            rs += __shfl_xor(rs, 32, 64);
            lrun += rs;

            unsigned int wA[2][4], wB[2][4];
#pragma unroll
            for (int nt = 0; nt < 2; ++nt)
#pragma unroll
                for (int rr = 0; rr < 4; ++rr) {
                    wA[nt][rr] = packbf2(sacc[nt][4 * rr + 0], sacc[nt][4 * rr + 1]);
                    wB[nt][rr] = packbf2(sacc[nt][4 * rr + 2], sacc[nt][4 * rr + 3]);
                }

            // PV: 4 k-slices of 16 kv; A-frag assembled via permlane32_swap (verified R3)
#pragma unroll
            for (int ks = 0; ks < 4; ++ks) {
                int nt = ks >> 1;
                int b2 = (ks & 1) * 2;
                auto rA = __builtin_amdgcn_permlane32_swap(wA[nt][b2], wA[nt][b2 + 1], false, false);
                auto rB = __builtin_amdgcn_permlane32_swap(wB[nt][b2], wB[nt][b2 + 1], false, false);
                uint4 pa;
                pa.x = rA[0];   // kv 16ks+8hi+{0,1}
                pa.y = rB[0];   // +{2,3}
                pa.z = rA[1];   // +{4,5}
                pa.w = rB[1];   // +{6,7}
                bf16x8 paf = __builtin_bit_cast(bf16x8, pa);
#pragma unroll
                for (int dt = 0; dt < 2; ++dt) {
                    bf16x8 vtf = load_frag(&Vt[dt * 32 + l31][ks * 16 + hi * 8]);
                    oacc[dt] = __builtin_amdgcn_mfma_f32_32x32x16_bf16(paf, vtf, oacc[dt], 0, 0, 0);
                }
            }
        }
    }

    float linv = 1.0f / lrun;
#pragma unroll
    for (int r = 0; r < 16; ++r) {
        int ql = (r & 3) + 8 * (r >> 2) + 4 * hi;
        float rv = __shfl(linv, ql, 64);
        int q = q0 + w * 32 + ql;
        size_t ro = ((size_t)(b * 2048 + q) * 16 + h) * 64;
        yb[ro + l31]      = f2bf(oacc[0][r] * rv);
        yb[ro + 32 + l31] = f2bf(oacc[1][r] * rv);
    }
#undef LOADT
}

// ---------- launch ----------
extern "C" void kernel_launch(void* const* d_in, const int* in_sizes, int n_in,
                              void* d_out, int out_size, void* d_ws, size_t ws_size,
                              hipStream_t stream) {
    const float* x      = (const float*)d_in[0];   // [2,2048,1024]
    const float* v1     = (const float*)d_in[1];   // [2,2048,16,64]
    const float* w_q    = (const float*)d_in[2];
    const float* w_k    = (const float*)d_in[3];
    const float* w_v    = (const float*)d_in[4];
    const float* w_proj = (const float*)d_in[5];
    const float* lamb   = (const float*)d_in[6];
    float* out = (float*)d_out;

    char* ws = (char*)d_ws;
    unsigned short* xb      = (unsigned short*)(ws + 0);           // 8MB
    unsigned short* wqkv_b  = (unsigned short*)(ws + (8u  << 20)); // 6MB
    unsigned short* wproj_b = (unsigned short*)(ws + (14u << 20)); // 2MB
    unsigned short* qkvb    = (unsigned short*)(ws + (16u << 20)); // bf16 [4096][3072] = 24MB
    unsigned short* vtp     = (unsigned short*)(ws + (40u << 20)); // [32][64][2048] = 8MB
    unsigned short* qbuf    = (unsigned short*)(ws + (48u << 20)); // 8MB
    unsigned short* kbuf    = (unsigned short*)(ws + (56u << 20)); // 8MB
    unsigned short* ybuf    = (unsigned short*)(ws + (64u << 20)); // 8MB
    float*          cost    = (float*)        (ws + (72u << 20));
    float*          sint    = (float*)        (ws + (72u << 20) + 262144);

    f32_to_bf16<<<16384, 256, 0, stream>>>(x, xb, 4096 * 1024);
    concat_w<<<12288, 256, 0, stream>>>(w_q, w_k, w_v, wqkv_b);
    f32_to_bf16<<<4096, 256, 0, stream>>>(w_proj, wproj_b, 1024 * 1024);
    rope_table<<<256, 256, 0, stream>>>(cost, sint);

    gemm_bf16<true><<<dim3(32, 24), 256, 0, stream>>>(xb, wqkv_b, (void*)qkvb, 3072, 1024);

    postprocess_qk<<<16384, 256, 0, stream>>>(qkvb, cost, sint, qbuf, kbuf);
    lerp_transpose_v<<<dim3(32, 32), 256, 0, stream>>>(qkvb, v1, lamb, vtp);

    attn<<<512, 256, 0, stream>>>(qbuf, kbuf, vtp, ybuf);

    gemm_bf16<false><<<dim3(32, 8), 256, 0, stream>>>(ybuf, wproj_b, (void*)out, 1024, 1024);

    hipMemcpyAsync(out + 4194304, v1, 4194304 * sizeof(float),
                   hipMemcpyDeviceToDevice, stream);
}